// Round 8
// baseline (460.674 us; speedup 1.0000x reference)
//
#include <hip/hip_runtime.h>
#include <hip/hip_bf16.h>

typedef __attribute__((ext_vector_type(4))) float f32x4;
typedef __attribute__((ext_vector_type(8))) short s16x8;
typedef __attribute__((ext_vector_type(4))) unsigned uintx4;

#define LQS 520   // row stride (shorts) = 1040 B (16B-aligned)

// ONE 66.5 KB buffer, lifetime-folded:
//   phase 1: cols [0,256) = x (bf16)
//   phase 2: cols [0,256)=Q, [256,512)=K  (wave-private 32-col slabs per head)
//   phase 3: la (attn out) overlays own Q slab, cols [0,256)
//   phase 4: fout (proj out, bf16) cols [256,512)
#define SMEM_BYTES (64 * LQS * 2)   // 66560 -> 2 blocks/CU

__device__ __forceinline__ unsigned cvt2bf(float a, float b) {
    unsigned r;
    asm("v_cvt_pk_bf16_f32 %0, %1, %2" : "=v"(r) : "v"(a), "v"(b));
    return r;
}

// K0: weights fp32 -> bf16
__global__ void wcvt_kernel(const float* __restrict__ qw, const float* __restrict__ pw,
                            short* __restrict__ wqkv, short* __restrict__ wproj) {
    int idx = blockIdx.x * blockDim.x + threadIdx.x;
    int stride = gridDim.x * blockDim.x;
    for (int i = idx; i < 65536; i += stride) {
        const float* src = (i < 49152) ? (qw + i * 4) : (pw + (i - 49152) * 4);
        unsigned* dst = (unsigned*)((i < 49152) ? (wqkv + i * 4) : (wproj + (i - 49152) * 4));
        const f32x4 v = *(const f32x4*)src;
        uint2 o = { cvt2bf(v.x, v.y), cvt2bf(v.z, v.w) };
        *(uint2*)dst = o;
    }
}

// K1: bias+mask table, log2 domain. bm[cls][head][i][j], cls=(wy==7)*2+(wx==7)
__global__ void bmgen_kernel(const float* __restrict__ rpb, float* __restrict__ bm) {
    int idx = blockIdx.x * blockDim.x + threadIdx.x;
    if (idx >= 131072) return;
    int j = idx & 63;
    int i = (idx >> 6) & 63;
    int h = (idx >> 12) & 7;
    int c = idx >> 15;
    int cy = c >> 1, cx = c & 1;
    float v;
    if (j >= 49) {
        v = -1e9f;
    } else {
        int ic = i > 48 ? 48 : i;
        int yi = ic / 7, xi = ic % 7;
        int yj = j / 7, xj = j % 7;
        float bias = rpb[((yi - yj + 6) * 13 + (xi - xj + 6)) * 8 + h];
        int ri = (cy ? (yi < 4 ? 1 : 2) : 0) * 3 + (cx ? (xi < 4 ? 1 : 2) : 0);
        int rj = (cy ? (yj < 4 ? 1 : 2) : 0) * 3 + (cx ? (xj < 4 ? 1 : 2) : 0);
        float mask = (ri != rj) ? -100.0f : 0.0f;
        v = (bias + mask) * 1.4426950408889634f;
    }
    bm[idx] = v;
}

__global__ __launch_bounds__(512, 4)
void swin_kernel(const float* __restrict__ x,
                 const float* __restrict__ qkv_bias,
                 const float* __restrict__ proj_bias,
                 const short* __restrict__ wqkv,
                 const short* __restrict__ wproj,
                 const float* __restrict__ bm,
                 float* __restrict__ out) {
    __shared__ __align__(16) short lqk[64 * LQS];

    const int tid  = threadIdx.x;
    const int h    = tid >> 6;        // wave id == head
    const int lane = tid & 63;
    const int il   = lane & 15;
    const int gl   = lane >> 4;

    const int b   = blockIdx.x >> 6;
    const int wid = blockIdx.x & 63;
    const int wy  = wid >> 3, wx = wid & 7;

    // ---------------- stage window x (bf16, cols 0..255) ----------------
    for (int i = tid; i < 4096; i += 512) {  // 64 rows x 64 float4 chunks
        int t = i >> 6, c4 = (i & 63) << 2;
        uint2 o;
        if (t < 49) {
            int ty = t / 7, tx = t % 7;
            int R = wy * 7 + ty + 3; if (R >= 56) R -= 56;
            int C = wx * 7 + tx + 3; if (C >= 56) C -= 56;
            const f32x4 v = *(const f32x4*)(x + (((b * 56 + R) * 56 + C) << 8) + c4);
            o.x = cvt2bf(v.x, v.y); o.y = cvt2bf(v.z, v.w);
        } else {
            o.x = 0; o.y = 0;
        }
        *(uint2*)&lqk[t * LQS + c4] = o;
    }
    __syncthreads();   // (1)

    // ---------------- QKV pass 1: V (head h, 32 cols) -> packed regs --------
    unsigned pv[4][2][2];
    {
        f32x4 vacc[4][2];
        #pragma unroll
        for (int mi = 0; mi < 4; mi++)
            #pragma unroll
            for (int md = 0; md < 2; md++) vacc[mi][md] = (f32x4){0.f, 0.f, 0.f, 0.f};
        for (int k0 = 0; k0 < 256; k0 += 32) {
            s16x8 a[4];
            #pragma unroll
            for (int mi = 0; mi < 4; mi++)
                a[mi] = *(const s16x8*)&lqk[(mi * 16 + il) * LQS + k0 + 8 * gl];
            #pragma unroll
            for (int md = 0; md < 2; md++) {
                s16x8 bfr = *(const s16x8*)(wqkv + (512 + 32 * h + 16 * md + il) * 256 + k0 + 8 * gl);
                #pragma unroll
                for (int mi = 0; mi < 4; mi++)
                    vacc[mi][md] = __builtin_amdgcn_mfma_f32_16x16x32_bf16(a[mi], bfr, vacc[mi][md], 0, 0, 0);
            }
        }
        #pragma unroll
        for (int md = 0; md < 2; md++) {
            float bv = qkv_bias[512 + 32 * h + 16 * md + il];
            #pragma unroll
            for (int mi = 0; mi < 4; mi++) {
                pv[mi][md][0] = cvt2bf(vacc[mi][md][0] + bv, vacc[mi][md][1] + bv);
                pv[mi][md][1] = cvt2bf(vacc[mi][md][2] + bv, vacc[mi][md][3] + bv);
            }
        }
    }

    // ---------------- QKV pass 2: Q,K (head h, 2x32 cols) -------------------
    {
        f32x4 acc[4][4];   // ni 0,1 = Q tiles; ni 2,3 = K tiles
        #pragma unroll
        for (int mi = 0; mi < 4; mi++)
            #pragma unroll
            for (int ni = 0; ni < 4; ni++) acc[mi][ni] = (f32x4){0.f, 0.f, 0.f, 0.f};
        for (int k0 = 0; k0 < 256; k0 += 32) {
            s16x8 a[4];
            #pragma unroll
            for (int mi = 0; mi < 4; mi++)
                a[mi] = *(const s16x8*)&lqk[(mi * 16 + il) * LQS + k0 + 8 * gl];
            #pragma unroll
            for (int ni = 0; ni < 4; ni++) {
                int col = (ni < 2) ? (32 * h + 16 * ni) : (256 + 32 * h + 16 * (ni - 2));
                s16x8 bfr = *(const s16x8*)(wqkv + (col + il) * 256 + k0 + 8 * gl);
                #pragma unroll
                for (int mi = 0; mi < 4; mi++)
                    acc[mi][ni] = __builtin_amdgcn_mfma_f32_16x16x32_bf16(a[mi], bfr, acc[mi][ni], 0, 0, 0);
            }
        }
        __syncthreads();   // (2) all x reads done; buffer becomes Q|K
        {
            const float QSCL = 0.17677669529663687f * 1.4426950408889634f;
            #pragma unroll
            for (int t = 0; t < 2; t++) {
                float bq_ = qkv_bias[32 * h + 16 * t + il];
                float bk_ = qkv_bias[256 + 32 * h + 16 * t + il];
                #pragma unroll
                for (int mi = 0; mi < 4; mi++)
                    #pragma unroll
                    for (int r = 0; r < 4; r++) {
                        int row = mi * 16 + gl * 4 + r;
                        unsigned u = cvt2bf((acc[mi][t][r] + bq_) * QSCL, acc[mi][t + 2][r] + bk_);
                        lqk[row * LQS + 32 * h + 16 * t + il] = (short)u;
                        lqk[row * LQS + 256 + 32 * h + 16 * t + il] = (short)(u >> 16);
                    }
            }
        }
    }
    // no barrier: Q|K slab is wave-private

    // ---------------- attention: head h, full rows, 2 key-halves ------------
    const int cls = ((wy == 7) ? 2 : 0) + ((wx == 7) ? 1 : 0);
    const float* bmp = bm + ((cls * 8 + h) * 64) * 64;

    f32x4 o[2][4];
    #pragma unroll
    for (int md = 0; md < 2; md++)
        #pragma unroll
        for (int ni = 0; ni < 4; ni++) o[md][ni] = (f32x4){0.f, 0.f, 0.f, 0.f};
    float l[4] = { 0.f, 0.f, 0.f, 0.f };

    #pragma unroll 1
    for (int half = 0; half < 2; half++) {
        // scores with bias+mask C-init (log2 domain)
        f32x4 s[2][4];
        #pragma unroll
        for (int mi = 0; mi < 2; mi++)
            #pragma unroll
            for (int ni = 0; ni < 4; ni++)
                s[mi][ni] = *(const f32x4*)&bmp[(ni * 16 + il) * 64 + half * 32 + mi * 16 + gl * 4];
        {
            // bq streamed per half (not held across halves)
            s16x8 bq[4];
            #pragma unroll
            for (int ni = 0; ni < 4; ni++)
                bq[ni] = *(const s16x8*)&lqk[(ni * 16 + il) * LQS + 32 * h + 8 * gl];
            #pragma unroll
            for (int mi = 0; mi < 2; mi++) {
                s16x8 ak = *(const s16x8*)&lqk[(half * 32 + mi * 16 + il) * LQS + 256 + 32 * h + 8 * gl];
                #pragma unroll
                for (int ni = 0; ni < 4; ni++)
                    s[mi][ni] = __builtin_amdgcn_mfma_f32_16x16x32_bf16(ak, bq[ni], s[mi][ni], 0, 0, 0);
            }
        }
        // p = 2^s; accumulate row partial sums
        #pragma unroll
        for (int mi = 0; mi < 2; mi++)
            #pragma unroll
            for (int ni = 0; ni < 4; ni++)
                #pragma unroll
                for (int r = 0; r < 4; r++) {
                    float p = exp2f(s[mi][ni][r]);
                    s[mi][ni][r] = p;
                    l[ni] += p;
                }
        // pack unnormalized P (s dies here)
        unsigned pkd[2][4][2];
        #pragma unroll
        for (int mi = 0; mi < 2; mi++)
            #pragma unroll
            for (int ni = 0; ni < 4; ni++) {
                pkd[mi][ni][0] = cvt2bf(s[mi][ni][0], s[mi][ni][1]);
                pkd[mi][ni][1] = cvt2bf(s[mi][ni][2], s[mi][ni][3]);
            }
        // V A-frags via shuffle (pv words selected inline by half)
        s16x8 av[2];
        #pragma unroll
        for (int md = 0; md < 2; md++) {
            unsigned wd[4];
            #pragma unroll
            for (int q = 0; q < 4; q++) {
                int src = (2 * (gl & 1) + (q >> 1)) * 16 + il;
                unsigned p0 = half ? pv[2][md][q & 1] : pv[0][md][q & 1];
                unsigned p1 = half ? pv[3][md][q & 1] : pv[1][md][q & 1];
                unsigned v0 = (unsigned)__shfl((int)p0, src);
                unsigned v1 = (unsigned)__shfl((int)p1, src);
                wd[q] = (gl & 2) ? v1 : v0;
            }
            union { unsigned u[4]; s16x8 v; } cv;
            cv.u[0] = wd[0]; cv.u[1] = wd[1]; cv.u[2] = wd[2]; cv.u[3] = wd[3];
            av[md] = cv.v;
        }
        // P B-frags via shuffle; PV accumulates into o
        #pragma unroll
        for (int ni = 0; ni < 4; ni++) {
            unsigned wd[4];
            #pragma unroll
            for (int q = 0; q < 4; q++) {
                int src = (2 * (gl & 1) + (q >> 1)) * 16 + il;
                unsigned v0 = (unsigned)__shfl((int)pkd[0][ni][q & 1], src);
                unsigned v1 = (unsigned)__shfl((int)pkd[1][ni][q & 1], src);
                wd[q] = (gl & 2) ? v1 : v0;
            }
            union { unsigned u[4]; s16x8 v; } cv;
            cv.u[0] = wd[0]; cv.u[1] = wd[1]; cv.u[2] = wd[2]; cv.u[3] = wd[3];
            #pragma unroll
            for (int md = 0; md < 2; md++)
                o[md][ni] = __builtin_amdgcn_mfma_f32_16x16x32_bf16(av[md], cv.v, o[md][ni], 0, 0, 0);
        }
    }
    // finish row sums, normalize, write la into own Q slab
    #pragma unroll
    for (int ni = 0; ni < 4; ni++) {
        l[ni] += __shfl_xor(l[ni], 16);
        l[ni] += __shfl_xor(l[ni], 32);
        l[ni] = __builtin_amdgcn_rcpf(l[ni]);
    }
    #pragma unroll
    for (int md = 0; md < 2; md++)
        #pragma unroll
        for (int ni = 0; ni < 4; ni++) {
            uint2 pk = { cvt2bf(o[md][ni][0] * l[ni], o[md][ni][1] * l[ni]),
                         cvt2bf(o[md][ni][2] * l[ni], o[md][ni][3] * l[ni]) };
            *(uint2*)&lqk[(ni * 16 + il) * LQS + 32 * h + md * 16 + gl * 4] = pk;
        }
    __syncthreads();   // (3) all la ready

    // ---------------- proj GEMM: wave h -> out cols [32h,32h+32) ------------
    {
        f32x4 acc[4][2];
        #pragma unroll
        for (int mi = 0; mi < 4; mi++)
            #pragma unroll
            for (int ni = 0; ni < 2; ni++) acc[mi][ni] = (f32x4){0.f, 0.f, 0.f, 0.f};
        for (int k0 = 0; k0 < 256; k0 += 32) {
            s16x8 a[4];
            #pragma unroll
            for (int mi = 0; mi < 4; mi++)
                a[mi] = *(const s16x8*)&lqk[(mi * 16 + il) * LQS + k0 + 8 * gl];
            #pragma unroll
            for (int ni = 0; ni < 2; ni++) {
                s16x8 bw = *(const s16x8*)(wproj + (32 * h + 16 * ni + il) * 256 + k0 + 8 * gl);
                #pragma unroll
                for (int mi = 0; mi < 4; mi++)
                    acc[mi][ni] = __builtin_amdgcn_mfma_f32_16x16x32_bf16(a[mi], bw, acc[mi][ni], 0, 0, 0);
            }
        }
        // fout (bf16) -> cols [256,512), K region (dead)
        #pragma unroll
        for (int ni = 0; ni < 2; ni++) {
            int oc = 32 * h + 16 * ni + il;
            float pb = proj_bias[oc];
            #pragma unroll
            for (int mi = 0; mi < 4; mi++)
                #pragma unroll
                for (int r = 0; r < 4; r++) {
                    int t = mi * 16 + gl * 4 + r;
                    if (t < 49) {
                        unsigned u = cvt2bf(acc[mi][ni][r] + pb, 0.f);
                        lqk[t * LQS + 256 + oc] = (short)u;
                    }
                }
        }
    }
    __syncthreads();   // (4)

    // ---------------- coalesced store with reverse roll ---------------------
    for (int i = tid; i < 1568; i += 512) {   // 49 rows x 32 chunks of 8 floats
        int t = i >> 5, c8 = (i & 31) << 3;
        uintx4 u = *(const uintx4*)&lqk[t * LQS + 256 + c8];
        f32x4 v0, v1;
        v0.x = __builtin_bit_cast(float, u.x << 16);
        v0.y = __builtin_bit_cast(float, u.x & 0xFFFF0000u);
        v0.z = __builtin_bit_cast(float, u.y << 16);
        v0.w = __builtin_bit_cast(float, u.y & 0xFFFF0000u);
        v1.x = __builtin_bit_cast(float, u.z << 16);
        v1.y = __builtin_bit_cast(float, u.z & 0xFFFF0000u);
        v1.z = __builtin_bit_cast(float, u.w << 16);
        v1.w = __builtin_bit_cast(float, u.w & 0xFFFF0000u);
        int ty = t / 7, tx = t % 7;
        int R = wy * 7 + ty + 3; if (R >= 56) R -= 56;
        int C = wx * 7 + tx + 3; if (C >= 56) C -= 56;
        float* op = out + (((b * 56 + R) * 56 + C) << 8) + c8;
        *(f32x4*)op = v0;
        *(f32x4*)(op + 4) = v1;
    }
}

extern "C" void kernel_launch(void* const* d_in, const int* in_sizes, int n_in,
                              void* d_out, int out_size, void* d_ws, size_t ws_size,
                              hipStream_t stream) {
    const float* x   = (const float*)d_in[0];
    const float* qw  = (const float*)d_in[1];
    const float* qb  = (const float*)d_in[2];
    const float* pw  = (const float*)d_in[3];
    const float* pb  = (const float*)d_in[4];
    const float* rpb = (const float*)d_in[5];

    short* wqkv  = (short*)d_ws;                       // 768*256 bf16
    short* wproj = wqkv + 768 * 256;                   // 256*256 bf16
    float* bmt   = (float*)((char*)d_ws + 524288);     // 4*8*64*64 f32

    wcvt_kernel<<<128, 256, 0, stream>>>(qw, pw, wqkv, wproj);
    bmgen_kernel<<<512, 256, 0, stream>>>(rpb, bmt);
    swin_kernel<<<2048, 512, 0, stream>>>(x, qb, pb, wqkv, wproj, bmt, (float*)d_out);
}

// Round 10
// 430.295 us; speedup vs baseline: 1.0706x; 1.0706x over previous
//
#include <hip/hip_runtime.h>
#include <hip/hip_bf16.h>

typedef __attribute__((ext_vector_type(4))) float f32x4;
typedef __attribute__((ext_vector_type(8))) short s16x8;
typedef __attribute__((ext_vector_type(4))) short s16x4;
typedef __attribute__((ext_vector_type(4))) unsigned uintx4;

#define LQS 520   // row stride (shorts) = 1040 B

// ONE 66.5 KB buffer, lifetime-folded:
//   phase 1: cols [0,256) = x (bf16)
//   phase 2: cols [0,256)=Q, [256,512)=K  (wave-private 32-col slabs per head)
//   phase 3: la (attn out) overlays own Q slab, cols [0,256)
//   phase 4: fout (proj out, bf16) cols [256,512)
#define SMEM_BYTES (64 * LQS * 2)   // 66560 -> 2 blocks/CU

__device__ __forceinline__ unsigned cvt2bf(float a, float b) {
    unsigned r;
    asm("v_cvt_pk_bf16_f32 %0, %1, %2" : "=v"(r) : "v"(a), "v"(b));
    return r;
}

__device__ __forceinline__ s16x4 pk4bf(float a, float b, float c, float d) {
    uint2 t = { cvt2bf(a, b), cvt2bf(c, d) };
    return __builtin_bit_cast(s16x4, t);
}

// [v0,v1,v2,v3] -> [v0,0,v1,0,v2,0,v3,0]: places 4-token acc runs at even
// virtual-k of a K=32 frag (k = 8*gl + 2r). Zeros contribute 0 to the MFMA.
__device__ __forceinline__ s16x8 expand_z(s16x4 c) {
    uint2 u = __builtin_bit_cast(uint2, c);
    uintx4 r = { u.x & 0xFFFFu, u.x >> 16, u.y & 0xFFFFu, u.y >> 16 };
    return __builtin_bit_cast(s16x8, r);
}

// K0: weights fp32 -> bf16
__global__ void wcvt_kernel(const float* __restrict__ qw, const float* __restrict__ pw,
                            short* __restrict__ wqkv, short* __restrict__ wproj) {
    int idx = blockIdx.x * blockDim.x + threadIdx.x;
    int stride = gridDim.x * blockDim.x;
    for (int i = idx; i < 65536; i += stride) {
        const float* src = (i < 49152) ? (qw + i * 4) : (pw + (i - 49152) * 4);
        unsigned* dst = (unsigned*)((i < 49152) ? (wqkv + i * 4) : (wproj + (i - 49152) * 4));
        const f32x4 v = *(const f32x4*)src;
        uint2 o = { cvt2bf(v.x, v.y), cvt2bf(v.z, v.w) };
        *(uint2*)dst = o;
    }
}

// K1: bias+mask table, log2 domain. bm[cls][head][i][j], cls=(wy==7)*2+(wx==7)
__global__ void bmgen_kernel(const float* __restrict__ rpb, float* __restrict__ bm) {
    int idx = blockIdx.x * blockDim.x + threadIdx.x;
    if (idx >= 131072) return;
    int j = idx & 63;
    int i = (idx >> 6) & 63;
    int h = (idx >> 12) & 7;
    int c = idx >> 15;
    int cy = c >> 1, cx = c & 1;
    float v;
    if (j >= 49) {
        v = -1e9f;
    } else {
        int ic = i > 48 ? 48 : i;
        int yi = ic / 7, xi = ic % 7;
        int yj = j / 7, xj = j % 7;
        float bias = rpb[((yi - yj + 6) * 13 + (xi - xj + 6)) * 8 + h];
        int ri = (cy ? (yi < 4 ? 1 : 2) : 0) * 3 + (cx ? (xi < 4 ? 1 : 2) : 0);
        int rj = (cy ? (yj < 4 ? 1 : 2) : 0) * 3 + (cx ? (xj < 4 ? 1 : 2) : 0);
        float mask = (ri != rj) ? -100.0f : 0.0f;
        v = (bias + mask) * 1.4426950408889634f;
    }
    bm[idx] = v;
}

__global__ __launch_bounds__(512, 4)
void swin_kernel(const float* __restrict__ x,
                 const float* __restrict__ qkv_bias,
                 const float* __restrict__ proj_bias,
                 const short* __restrict__ wqkv,
                 const short* __restrict__ wproj,
                 const float* __restrict__ bm,
                 float* __restrict__ out) {
    __shared__ __align__(16) short lqk[64 * LQS];

    const int tid  = threadIdx.x;
    const int h    = tid >> 6;        // wave id == head
    const int lane = tid & 63;
    const int il   = lane & 15;
    const int gl   = lane >> 4;

    const int b   = blockIdx.x >> 6;
    const int wid = blockIdx.x & 63;
    const int wy  = wid >> 3, wx = wid & 7;

    // ---------------- stage window x (bf16, cols 0..255) ----------------
    for (int i = tid; i < 4096; i += 512) {  // 64 rows x 64 float4 chunks
        int t = i >> 6, c4 = (i & 63) << 2;
        uint2 o;
        if (t < 49) {
            int ty = t / 7, tx = t % 7;
            int R = wy * 7 + ty + 3; if (R >= 56) R -= 56;
            int C = wx * 7 + tx + 3; if (C >= 56) C -= 56;
            const f32x4 v = *(const f32x4*)(x + (((b * 56 + R) * 56 + C) << 8) + c4);
            o.x = cvt2bf(v.x, v.y); o.y = cvt2bf(v.z, v.w);
        } else {
            o.x = 0; o.y = 0;
        }
        *(uint2*)&lqk[t * LQS + c4] = o;
    }
    __syncthreads();   // (1)

    // ---------------- QKV pass 1: V (head h, 32 cols) -> compact frag regs --
    // pv[mi][md]: tokens mi*16 + 4gl + r (r=0..3), d = 16*md + il.
    s16x4 pv[4][2];
    {
        f32x4 vacc[4][2];
        #pragma unroll
        for (int mi = 0; mi < 4; mi++)
            #pragma unroll
            for (int md = 0; md < 2; md++) vacc[mi][md] = (f32x4){0.f, 0.f, 0.f, 0.f};
        for (int k0 = 0; k0 < 256; k0 += 32) {
            s16x8 a[4];
            #pragma unroll
            for (int mi = 0; mi < 4; mi++)
                a[mi] = *(const s16x8*)&lqk[(mi * 16 + il) * LQS + k0 + 8 * gl];
            #pragma unroll
            for (int md = 0; md < 2; md++) {
                s16x8 bfr = *(const s16x8*)(wqkv + (512 + 32 * h + 16 * md + il) * 256 + k0 + 8 * gl);
                #pragma unroll
                for (int mi = 0; mi < 4; mi++)
                    vacc[mi][md] = __builtin_amdgcn_mfma_f32_16x16x32_bf16(a[mi], bfr, vacc[mi][md], 0, 0, 0);
            }
        }
        #pragma unroll
        for (int md = 0; md < 2; md++) {
            float bv = qkv_bias[512 + 32 * h + 16 * md + il];
            #pragma unroll
            for (int mi = 0; mi < 4; mi++)
                pv[mi][md] = pk4bf(vacc[mi][md][0] + bv, vacc[mi][md][1] + bv,
                                   vacc[mi][md][2] + bv, vacc[mi][md][3] + bv);
        }
    }

    // ---------------- QKV pass 2: Q,K (head h, 2x32 cols) -------------------
    {
        f32x4 acc[4][4];   // ni 0,1 = Q tiles; ni 2,3 = K tiles
        #pragma unroll
        for (int mi = 0; mi < 4; mi++)
            #pragma unroll
            for (int ni = 0; ni < 4; ni++) acc[mi][ni] = (f32x4){0.f, 0.f, 0.f, 0.f};
        for (int k0 = 0; k0 < 256; k0 += 32) {
            s16x8 a[4];
            #pragma unroll
            for (int mi = 0; mi < 4; mi++)
                a[mi] = *(const s16x8*)&lqk[(mi * 16 + il) * LQS + k0 + 8 * gl];
            #pragma unroll
            for (int ni = 0; ni < 4; ni++) {
                int col = (ni < 2) ? (32 * h + 16 * ni) : (256 + 32 * h + 16 * (ni - 2));
                s16x8 bfr = *(const s16x8*)(wqkv + (col + il) * 256 + k0 + 8 * gl);
                #pragma unroll
                for (int mi = 0; mi < 4; mi++)
                    acc[mi][ni] = __builtin_amdgcn_mfma_f32_16x16x32_bf16(a[mi], bfr, acc[mi][ni], 0, 0, 0);
            }
        }
        __syncthreads();   // (2) all x reads done; buffer becomes Q|K
        {
            const float QSCL = 0.17677669529663687f * 1.4426950408889634f;
            #pragma unroll
            for (int t = 0; t < 2; t++) {
                float bq_ = qkv_bias[32 * h + 16 * t + il];
                float bk_ = qkv_bias[256 + 32 * h + 16 * t + il];
                #pragma unroll
                for (int mi = 0; mi < 4; mi++)
                    #pragma unroll
                    for (int r = 0; r < 4; r++) {
                        int row = mi * 16 + gl * 4 + r;
                        unsigned u = cvt2bf((acc[mi][t][r] + bq_) * QSCL, acc[mi][t + 2][r] + bk_);
                        lqk[row * LQS + 32 * h + 16 * t + il] = (short)u;
                        lqk[row * LQS + 256 + 32 * h + 16 * t + il] = (short)(u >> 16);
                    }
            }
        }
    }
    // no barrier: Q|K slab is wave-private

    // ---------------- attention: head h, full rows, 2 key-halves ------------
    const int cls = ((wy == 7) ? 2 : 0) + ((wx == 7) ? 1 : 0);
    const float* bmp = bm + ((cls * 8 + h) * 64) * 64;

    f32x4 o[2][4];
    #pragma unroll
    for (int md = 0; md < 2; md++)
        #pragma unroll
        for (int ni = 0; ni < 4; ni++) o[md][ni] = (f32x4){0.f, 0.f, 0.f, 0.f};
    float l[4] = { 0.f, 0.f, 0.f, 0.f };

    #pragma unroll 1
    for (int half = 0; half < 2; half++) {
        // scores with bias+mask C-init (log2 domain)
        f32x4 s[2][4];
        #pragma unroll
        for (int mi = 0; mi < 2; mi++)
            #pragma unroll
            for (int ni = 0; ni < 4; ni++)
                s[mi][ni] = *(const f32x4*)&bmp[(ni * 16 + il) * 64 + half * 32 + mi * 16 + gl * 4];
        {
            s16x8 bq[4];
            #pragma unroll
            for (int ni = 0; ni < 4; ni++)
                bq[ni] = *(const s16x8*)&lqk[(ni * 16 + il) * LQS + 32 * h + 8 * gl];
            #pragma unroll
            for (int mi = 0; mi < 2; mi++) {
                s16x8 ak = *(const s16x8*)&lqk[(half * 32 + mi * 16 + il) * LQS + 256 + 32 * h + 8 * gl];
                #pragma unroll
                for (int ni = 0; ni < 4; ni++)
                    s[mi][ni] = __builtin_amdgcn_mfma_f32_16x16x32_bf16(ak, bq[ni], s[mi][ni], 0, 0, 0);
            }
        }
        // p = 2^s; row partial sums; pack compact [p0,p1,p2,p3] (s dies)
        s16x4 pkd[2][4];
        #pragma unroll
        for (int mi = 0; mi < 2; mi++)
            #pragma unroll
            for (int ni = 0; ni < 4; ni++) {
                float p0 = exp2f(s[mi][ni][0]);
                float p1 = exp2f(s[mi][ni][1]);
                float p2 = exp2f(s[mi][ni][2]);
                float p3 = exp2f(s[mi][ni][3]);
                l[ni] += (p0 + p1) + (p2 + p3);
                pkd[mi][ni] = pk4bf(p0, p1, p2, p3);
            }
        // PV via K=32 MFMA with even-k interleave: zero-shuffle fragments.
        #pragma unroll
        for (int mi = 0; mi < 2; mi++) {
            s16x8 pa0 = expand_z(half ? pv[2 + mi][0] : pv[mi][0]);
            s16x8 pa1 = expand_z(half ? pv[2 + mi][1] : pv[mi][1]);
            #pragma unroll
            for (int ni = 0; ni < 4; ni++) {
                s16x8 bp = expand_z(pkd[mi][ni]);
                o[0][ni] = __builtin_amdgcn_mfma_f32_16x16x32_bf16(pa0, bp, o[0][ni], 0, 0, 0);
                o[1][ni] = __builtin_amdgcn_mfma_f32_16x16x32_bf16(pa1, bp, o[1][ni], 0, 0, 0);
            }
        }
    }
    // finish row sums, normalize, write la into own Q slab
    #pragma unroll
    for (int ni = 0; ni < 4; ni++) {
        l[ni] += __shfl_xor(l[ni], 16);
        l[ni] += __shfl_xor(l[ni], 32);
        l[ni] = __builtin_amdgcn_rcpf(l[ni]);
    }
    #pragma unroll
    for (int md = 0; md < 2; md++)
        #pragma unroll
        for (int ni = 0; ni < 4; ni++) {
            uint2 pk = { cvt2bf(o[md][ni][0] * l[ni], o[md][ni][1] * l[ni]),
                         cvt2bf(o[md][ni][2] * l[ni], o[md][ni][3] * l[ni]) };
            *(uint2*)&lqk[(ni * 16 + il) * LQS + 32 * h + md * 16 + gl * 4] = pk;
        }
    __syncthreads();   // (3) all la ready

    // ---------------- proj GEMM: wave h -> out cols [32h,32h+32) ------------
    {
        f32x4 acc[4][2];
        #pragma unroll
        for (int mi = 0; mi < 4; mi++)
            #pragma unroll
            for (int ni = 0; ni < 2; ni++) acc[mi][ni] = (f32x4){0.f, 0.f, 0.f, 0.f};
        for (int k0 = 0; k0 < 256; k0 += 32) {
            s16x8 a[4];
            #pragma unroll
            for (int mi = 0; mi < 4; mi++)
                a[mi] = *(const s16x8*)&lqk[(mi * 16 + il) * LQS + k0 + 8 * gl];
            #pragma unroll
            for (int ni = 0; ni < 2; ni++) {
                s16x8 bw = *(const s16x8*)(wproj + (32 * h + 16 * ni + il) * 256 + k0 + 8 * gl);
                #pragma unroll
                for (int mi = 0; mi < 4; mi++)
                    acc[mi][ni] = __builtin_amdgcn_mfma_f32_16x16x32_bf16(a[mi], bw, acc[mi][ni], 0, 0, 0);
            }
        }
        // fout (bf16) -> cols [256,512): disjoint from all waves' la reads
        #pragma unroll
        for (int ni = 0; ni < 2; ni++) {
            int oc = 32 * h + 16 * ni + il;
            float pb = proj_bias[oc];
            #pragma unroll
            for (int mi = 0; mi < 4; mi++)
                #pragma unroll
                for (int r = 0; r < 4; r++) {
                    int t = mi * 16 + gl * 4 + r;
                    if (t < 49) {
                        unsigned u = cvt2bf(acc[mi][ni][r] + pb, 0.f);
                        lqk[t * LQS + 256 + oc] = (short)u;
                    }
                }
        }
    }
    __syncthreads();   // (4)

    // ---------------- coalesced store with reverse roll ---------------------
    for (int i = tid; i < 1568; i += 512) {   // 49 rows x 32 chunks of 8 floats
        int t = i >> 5, c8 = (i & 31) << 3;
        uintx4 u = *(const uintx4*)&lqk[t * LQS + 256 + c8];
        f32x4 v0, v1;
        v0.x = __builtin_bit_cast(float, u.x << 16);
        v0.y = __builtin_bit_cast(float, u.x & 0xFFFF0000u);
        v0.z = __builtin_bit_cast(float, u.y << 16);
        v0.w = __builtin_bit_cast(float, u.y & 0xFFFF0000u);
        v1.x = __builtin_bit_cast(float, u.z << 16);
        v1.y = __builtin_bit_cast(float, u.z & 0xFFFF0000u);
        v1.z = __builtin_bit_cast(float, u.w << 16);
        v1.w = __builtin_bit_cast(float, u.w & 0xFFFF0000u);
        int ty = t / 7, tx = t % 7;
        int R = wy * 7 + ty + 3; if (R >= 56) R -= 56;
        int C = wx * 7 + tx + 3; if (C >= 56) C -= 56;
        float* op = out + (((b * 56 + R) * 56 + C) << 8) + c8;
        *(f32x4*)op = v0;
        *(f32x4*)(op + 4) = v1;
    }
}

extern "C" void kernel_launch(void* const* d_in, const int* in_sizes, int n_in,
                              void* d_out, int out_size, void* d_ws, size_t ws_size,
                              hipStream_t stream) {
    const float* x   = (const float*)d_in[0];
    const float* qw  = (const float*)d_in[1];
    const float* qb  = (const float*)d_in[2];
    const float* pw  = (const float*)d_in[3];
    const float* pb  = (const float*)d_in[4];
    const float* rpb = (const float*)d_in[5];

    short* wqkv  = (short*)d_ws;                       // 768*256 bf16
    short* wproj = wqkv + 768 * 256;                   // 256*256 bf16
    float* bmt   = (float*)((char*)d_ws + 524288);     // 4*8*64*64 f32

    wcvt_kernel<<<128, 256, 0, stream>>>(qw, pw, wqkv, wproj);
    bmgen_kernel<<<512, 256, 0, stream>>>(rpb, bmt);
    swin_kernel<<<2048, 512, 0, stream>>>(x, qb, pb, wqkv, wproj, bmt, (float*)d_out);
}

// Round 12
// 227.255 us; speedup vs baseline: 2.0271x; 1.8935x over previous
//
#include <hip/hip_runtime.h>
#include <hip/hip_bf16.h>

typedef __attribute__((ext_vector_type(4))) float f32x4;
typedef __attribute__((ext_vector_type(8))) short s16x8;
typedef __attribute__((ext_vector_type(4))) short s16x4;
typedef __attribute__((ext_vector_type(4))) unsigned uintx4;

#define LBS 264   // buf row stride (shorts): 256 + 8 pad
#define VTS 72    // VT row stride (shorts)
#define LOS 132   // lout row stride (f32) — overlays buf exactly (64*132*4 = 64*264*2)

__device__ __forceinline__ unsigned cvt2bf(float a, float b) {
    unsigned r;
    asm("v_cvt_pk_bf16_f32 %0, %1, %2" : "=v"(r) : "v"(a), "v"(b));
    return r;
}

__device__ __forceinline__ s16x4 pk4bf(float a, float b, float c, float d) {
    uint2 t = { cvt2bf(a, b), cvt2bf(c, d) };
    return __builtin_bit_cast(s16x4, t);
}

// [v0,v1,v2,v3] -> [v0,0,v1,0,v2,0,v3,0]: token (4gl+r) at virtual k=8gl+2r of a
// K=32 fragment; zeros at odd k contribute nothing. (Verified R10.)
__device__ __forceinline__ s16x8 expand_z(s16x4 c) {
    uint2 u = __builtin_bit_cast(uint2, c);
    uintx4 r = { u.x & 0xFFFFu, u.x >> 16, u.y & 0xFFFFu, u.y >> 16 };
    return __builtin_bit_cast(s16x8, r);
}

// K0: weights fp32 -> bf16
__global__ void wcvt_kernel(const float* __restrict__ qw, const float* __restrict__ pw,
                            short* __restrict__ wqkv, short* __restrict__ wproj) {
    int idx = blockIdx.x * blockDim.x + threadIdx.x;
    int stride = gridDim.x * blockDim.x;
    for (int i = idx; i < 65536; i += stride) {
        const float* src = (i < 49152) ? (qw + i * 4) : (pw + (i - 49152) * 4);
        unsigned* dst = (unsigned*)((i < 49152) ? (wqkv + i * 4) : (wproj + (i - 49152) * 4));
        const f32x4 v = *(const f32x4*)src;
        uint2 o = { cvt2bf(v.x, v.y), cvt2bf(v.z, v.w) };
        *(uint2*)dst = o;
    }
}

// K1: bias+mask table, log2 domain. bm[cls][head][i][j], cls=(wy==7)*2+(wx==7)
__global__ void bmgen_kernel(const float* __restrict__ rpb, float* __restrict__ bm) {
    int idx = blockIdx.x * blockDim.x + threadIdx.x;
    if (idx >= 131072) return;
    int j = idx & 63;
    int i = (idx >> 6) & 63;
    int h = (idx >> 12) & 7;
    int c = idx >> 15;
    int cy = c >> 1, cx = c & 1;
    float v;
    if (j >= 49) {
        v = -1e9f;
    } else {
        int ic = i > 48 ? 48 : i;
        int yi = ic / 7, xi = ic % 7;
        int yj = j / 7, xj = j % 7;
        float bias = rpb[((yi - yj + 6) * 13 + (xi - xj + 6)) * 8 + h];
        int ri = (cy ? (yi < 4 ? 1 : 2) : 0) * 3 + (cx ? (xi < 4 ? 1 : 2) : 0);
        int rj = (cy ? (yj < 4 ? 1 : 2) : 0) * 3 + (cx ? (xj < 4 ? 1 : 2) : 0);
        float mask = (ri != rj) ? -100.0f : 0.0f;
        v = (bias + mask) * 1.4426950408889634f;
    }
    bm[idx] = v;
}

// K2: attention. Block = (window, 4-head group). 8 waves = (hl in 0..3, jh in 0..1).
// Writes la[win*49 + t][256] bf16 (this block's 128 channels).
__global__ __launch_bounds__(512, 2)
void attn_kernel(const float* __restrict__ x,
                 const float* __restrict__ qkv_bias,
                 const short* __restrict__ wqkv,
                 const float* __restrict__ bm,
                 unsigned short* __restrict__ la) {
    __shared__ __align__(16) short buf[64 * LBS];   // x -> Q|K -> lout(f32)
    __shared__ __align__(16) short lvt[128 * VTS];  // V^T, 4 heads (local cols 0..127)
    __shared__ float lml[8 * 64];                   // [(hl*2+jh)*64 + i] partial sums

    const int tid  = threadIdx.x;
    const int w    = tid >> 6;        // wave 0..7
    const int lane = tid & 63;
    const int il   = lane & 15;
    const int gl   = lane >> 4;
    const int hl   = w >> 1;          // head-local 0..3
    const int jh   = w & 1;           // key-half

    const int hg  = blockIdx.x & 1;
    const int win = blockIdx.x >> 1;
    const int wid = win & 63;
    const int b   = win >> 6;
    const int wy  = wid >> 3, wx = wid & 7;

    // ---------------- stage window x (bf16, cols 0..255) --------------------
    for (int i = tid; i < 4096; i += 512) {  // 64 rows x 64 float4 chunks
        int t = i >> 6, c4 = (i & 63) << 2;
        uint2 o;
        if (t < 49) {
            int ty = t / 7, tx = t % 7;
            int R = wy * 7 + ty + 3; if (R >= 56) R -= 56;
            int C = wx * 7 + tx + 3; if (C >= 56) C -= 56;
            const f32x4 v = *(const f32x4*)(x + (((b * 56 + R) * 56 + C) << 8) + c4);
            o.x = cvt2bf(v.x, v.y); o.y = cvt2bf(v.z, v.w);
        } else {
            o.x = 0; o.y = 0;
        }
        *(uint2*)&buf[t * LBS + c4] = o;
    }
    __syncthreads();   // (1)

    // ---------------- QKV GEMM: wave w -> 16 cols each of Q,K,V -------------
    {
        f32x4 acc[4][3];
        #pragma unroll
        for (int mi = 0; mi < 4; mi++)
            #pragma unroll
            for (int t = 0; t < 3; t++) acc[mi][t] = (f32x4){0.f, 0.f, 0.f, 0.f};
        for (int k0 = 0; k0 < 256; k0 += 32) {
            s16x8 a[4];
            #pragma unroll
            for (int mi = 0; mi < 4; mi++)
                a[mi] = *(const s16x8*)&buf[(mi * 16 + il) * LBS + k0 + 8 * gl];
            #pragma unroll
            for (int t = 0; t < 3; t++) {
                s16x8 bfr = *(const s16x8*)(wqkv + (t * 256 + hg * 128 + 16 * w + il) * 256 + k0 + 8 * gl);
                #pragma unroll
                for (int mi = 0; mi < 4; mi++)
                    acc[mi][t] = __builtin_amdgcn_mfma_f32_16x16x32_bf16(a[mi], bfr, acc[mi][t], 0, 0, 0);
            }
        }
        // V -> lvt (transposed; row = local v-col, col = token), disjoint region
        {
            float bv = qkv_bias[512 + hg * 128 + 16 * w + il];
            #pragma unroll
            for (int mi = 0; mi < 4; mi++)
                *(s16x4*)&lvt[(16 * w + il) * VTS + mi * 16 + gl * 4] =
                    pk4bf(acc[mi][2][0] + bv, acc[mi][2][1] + bv,
                          acc[mi][2][2] + bv, acc[mi][2][3] + bv);
        }
        __syncthreads();   // (2) x reads done; buf -> Q|K
        {
            const float QSCL = 0.17677669529663687f * 1.4426950408889634f;
            float bq_ = qkv_bias[hg * 128 + 16 * w + il];
            float bk_ = qkv_bias[256 + hg * 128 + 16 * w + il];
            #pragma unroll
            for (int mi = 0; mi < 4; mi++)
                #pragma unroll
                for (int r = 0; r < 4; r++) {
                    int row = mi * 16 + gl * 4 + r;
                    unsigned u = cvt2bf((acc[mi][0][r] + bq_) * QSCL, acc[mi][1][r] + bk_);
                    buf[row * LBS + 16 * w + il] = (short)u;                 // Q local col
                    buf[row * LBS + 128 + 16 * w + il] = (short)(u >> 16);   // K local col
                }
        }
    }
    __syncthreads();   // (3) Q,K,VT ready

    // ---------------- attention: wave (hl, jh), keys [32jh, 32jh+32) --------
    const int cls = ((wy == 7) ? 2 : 0) + ((wx == 7) ? 1 : 0);
    const float* bmp = bm + ((cls * 8 + hg * 4 + hl) * 64) * 64;

    f32x4 s[2][4];
    #pragma unroll
    for (int mi = 0; mi < 2; mi++)
        #pragma unroll
        for (int ni = 0; ni < 4; ni++)
            s[mi][ni] = *(const f32x4*)&bmp[(ni * 16 + il) * 64 + jh * 32 + mi * 16 + gl * 4];
    {
        s16x8 bq[4];
        #pragma unroll
        for (int ni = 0; ni < 4; ni++)
            bq[ni] = *(const s16x8*)&buf[(ni * 16 + il) * LBS + hl * 32 + 8 * gl];
        #pragma unroll
        for (int mi = 0; mi < 2; mi++) {
            s16x8 ak = *(const s16x8*)&buf[(jh * 32 + mi * 16 + il) * LBS + 128 + hl * 32 + 8 * gl];
            #pragma unroll
            for (int ni = 0; ni < 4; ni++)
                s[mi][ni] = __builtin_amdgcn_mfma_f32_16x16x32_bf16(ak, bq[ni], s[mi][ni], 0, 0, 0);
        }
    }
    // p = 2^s (log2 domain, no max); partial row sums; pack compact
    float l[4] = { 0.f, 0.f, 0.f, 0.f };
    s16x4 pkd[2][4];
    #pragma unroll
    for (int mi = 0; mi < 2; mi++)
        #pragma unroll
        for (int ni = 0; ni < 4; ni++) {
            float p0 = exp2f(s[mi][ni][0]);
            float p1 = exp2f(s[mi][ni][1]);
            float p2 = exp2f(s[mi][ni][2]);
            float p3 = exp2f(s[mi][ni][3]);
            l[ni] += (p0 + p1) + (p2 + p3);
            pkd[mi][ni] = pk4bf(p0, p1, p2, p3);
        }
    #pragma unroll
    for (int ni = 0; ni < 4; ni++) {
        l[ni] += __shfl_xor(l[ni], 16);
        l[ni] += __shfl_xor(l[ni], 32);
    }
    if (jh == 0 && gl == 0) {
        #pragma unroll
        for (int ni = 0; ni < 4; ni++) lml[(hl * 2) * 64 + ni * 16 + il] = l[ni];
    }
    __syncthreads();   // (4) lml visible; Q|K frag reads done -> buf free for lout

    // PV: o^T[d][i] += V^T[d][j] P[j][i], zero-shuffle even-k fragments
    f32x4 o[2][4];
    #pragma unroll
    for (int md = 0; md < 2; md++)
        #pragma unroll
        for (int ni = 0; ni < 4; ni++) o[md][ni] = (f32x4){0.f, 0.f, 0.f, 0.f};
    #pragma unroll
    for (int mi = 0; mi < 2; mi++) {
        s16x8 av[2];
        #pragma unroll
        for (int md = 0; md < 2; md++)
            av[md] = expand_z(*(const s16x4*)&lvt[(hl * 32 + md * 16 + il) * VTS + jh * 32 + mi * 16 + 4 * gl]);
        #pragma unroll
        for (int ni = 0; ni < 4; ni++) {
            s16x8 bp = expand_z(pkd[mi][ni]);
            #pragma unroll
            for (int md = 0; md < 2; md++)
                o[md][ni] = __builtin_amdgcn_mfma_f32_16x16x32_bf16(av[md], bp, o[md][ni], 0, 0, 0);
        }
    }
    float* lout = (float*)buf;   // [64][LOS]
    if (jh == 0) {
        #pragma unroll
        for (int md = 0; md < 2; md++)
            #pragma unroll
            for (int ni = 0; ni < 4; ni++)
                *(f32x4*)&lout[(ni * 16 + il) * LOS + hl * 32 + md * 16 + gl * 4] = o[md][ni];
    }
    __syncthreads();   // (5)
    if (jh == 1) {
        float sc[4];
        #pragma unroll
        for (int ni = 0; ni < 4; ni++)
            sc[ni] = __builtin_amdgcn_rcpf(l[ni] + lml[(hl * 2) * 64 + ni * 16 + il]);
        #pragma unroll
        for (int ni = 0; ni < 4; ni++) {
            int i = ni * 16 + il;
            if (i < 49) {
                #pragma unroll
                for (int md = 0; md < 2; md++) {
                    f32x4 t = *(const f32x4*)&lout[i * LOS + hl * 32 + md * 16 + gl * 4];
                    uint2 pk = { cvt2bf((t.x + o[md][ni][0]) * sc[ni], (t.y + o[md][ni][1]) * sc[ni]),
                                 cvt2bf((t.z + o[md][ni][2]) * sc[ni], (t.w + o[md][ni][3]) * sc[ni]) };
                    *(uint2*)&la[(win * 49 + i) * 256 + hg * 128 + hl * 32 + md * 16 + gl * 4] = pk;
                }
            }
        }
    }
}

// K3: proj GEMM + reverse-roll store. Block = window, 8 waves.
__global__ __launch_bounds__(512, 2)
void proj_kernel(const unsigned short* __restrict__ la,
                 const float* __restrict__ proj_bias,
                 const short* __restrict__ wproj,
                 float* __restrict__ out) {
    __shared__ __align__(16) short buf[64 * LBS];   // la -> fout(bf16)

    const int tid  = threadIdx.x;
    const int w    = tid >> 6;
    const int lane = tid & 63;
    const int il   = lane & 15;
    const int gl   = lane >> 4;

    const int win = blockIdx.x;
    const int wid = win & 63;
    const int b   = win >> 6;
    const int wy  = wid >> 3, wx = wid & 7;

    // stage la (bf16 rows, coalesced, 16B chunks); zero rows 49..63
    for (int i = tid; i < 2048; i += 512) {   // 64 rows x 32 chunks of 8 shorts
        int t = i >> 5, c8 = (i & 31) << 3;
        uintx4 v = (t < 49) ? *(const uintx4*)&la[(win * 49 + t) * 256 + c8]
                            : (uintx4){0u, 0u, 0u, 0u};
        *(uintx4*)&buf[t * LBS + c8] = v;
    }
    __syncthreads();   // (1)

    f32x4 acc[4][2];
    #pragma unroll
    for (int mi = 0; mi < 4; mi++)
        #pragma unroll
        for (int ni = 0; ni < 2; ni++) acc[mi][ni] = (f32x4){0.f, 0.f, 0.f, 0.f};
    for (int k0 = 0; k0 < 256; k0 += 32) {
        s16x8 a[4];
        #pragma unroll
        for (int mi = 0; mi < 4; mi++)
            a[mi] = *(const s16x8*)&buf[(mi * 16 + il) * LBS + k0 + 8 * gl];
        #pragma unroll
        for (int ni = 0; ni < 2; ni++) {
            s16x8 bw = *(const s16x8*)(wproj + (32 * w + 16 * ni + il) * 256 + k0 + 8 * gl);
            #pragma unroll
            for (int mi = 0; mi < 4; mi++)
                acc[mi][ni] = __builtin_amdgcn_mfma_f32_16x16x32_bf16(a[mi], bw, acc[mi][ni], 0, 0, 0);
        }
    }
    __syncthreads();   // (2) la reads done; buf -> fout (bf16)
    #pragma unroll
    for (int ni = 0; ni < 2; ni++) {
        int oc = 32 * w + 16 * ni + il;
        float pb = proj_bias[oc];
        #pragma unroll
        for (int mi = 0; mi < 4; mi++)
            #pragma unroll
            for (int r = 0; r < 4; r++) {
                int t = mi * 16 + gl * 4 + r;
                if (t < 49) {
                    unsigned u = cvt2bf(acc[mi][ni][r] + pb, 0.f);
                    buf[t * LBS + oc] = (short)u;
                }
            }
    }
    __syncthreads();   // (3)
    // coalesced store with reverse roll: full 1KB token rows
    for (int i = tid; i < 1568; i += 512) {   // 49 rows x 32 chunks of 8 floats
        int t = i >> 5, c8 = (i & 31) << 3;
        uintx4 u = *(const uintx4*)&buf[t * LBS + c8];
        f32x4 v0, v1;
        v0.x = __builtin_bit_cast(float, u.x << 16);
        v0.y = __builtin_bit_cast(float, u.x & 0xFFFF0000u);
        v0.z = __builtin_bit_cast(float, u.y << 16);
        v0.w = __builtin_bit_cast(float, u.y & 0xFFFF0000u);
        v1.x = __builtin_bit_cast(float, u.z << 16);
        v1.y = __builtin_bit_cast(float, u.z & 0xFFFF0000u);
        v1.z = __builtin_bit_cast(float, u.w << 16);
        v1.w = __builtin_bit_cast(float, u.w & 0xFFFF0000u);
        int ty = t / 7, tx = t % 7;
        int R = wy * 7 + ty + 3; if (R >= 56) R -= 56;
        int C = wx * 7 + tx + 3; if (C >= 56) C -= 56;
        float* op = out + (((b * 56 + R) * 56 + C) << 8) + c8;
        *(f32x4*)op = v0;
        *(f32x4*)(op + 4) = v1;
    }
}

extern "C" void kernel_launch(void* const* d_in, const int* in_sizes, int n_in,
                              void* d_out, int out_size, void* d_ws, size_t ws_size,
                              hipStream_t stream) {
    const float* x   = (const float*)d_in[0];
    const float* qw  = (const float*)d_in[1];
    const float* qb  = (const float*)d_in[2];
    const float* pw  = (const float*)d_in[3];
    const float* pb  = (const float*)d_in[4];
    const float* rpb = (const float*)d_in[5];

    short* wqkv  = (short*)d_ws;                            // 768*256 bf16
    short* wproj = wqkv + 768 * 256;                        // 256*256 bf16
    float* bmt   = (float*)((char*)d_ws + 524288);          // 4*8*64*64 f32
    unsigned short* lat = (unsigned short*)((char*)d_ws + 2097152);  // 2048*49*256 bf16 = 51.4 MB

    wcvt_kernel<<<128, 256, 0, stream>>>(qw, pw, wqkv, wproj);
    bmgen_kernel<<<512, 256, 0, stream>>>(rpb, bmt);
    attn_kernel<<<4096, 512, 0, stream>>>(x, qb, wqkv, bmt, lat);
    proj_kernel<<<2048, 512, 0, stream>>>(lat, pb, wproj, (float*)d_out);
}

// Round 13
// 226.485 us; speedup vs baseline: 2.0340x; 1.0034x over previous
//
#include <hip/hip_runtime.h>
#include <hip/hip_bf16.h>

typedef __attribute__((ext_vector_type(4))) float f32x4;
typedef __attribute__((ext_vector_type(8))) short s16x8;
typedef __attribute__((ext_vector_type(4))) short s16x4;
typedef __attribute__((ext_vector_type(4))) unsigned uintx4;

#define LBS 264   // buf row stride (shorts): 256 + 8 pad
#define VTS 72    // VT row stride (shorts)
#define LOS 132   // lout row stride (f32) — overlays buf exactly (64*132*4 = 64*264*2)

__device__ __forceinline__ unsigned cvt2bf(float a, float b) {
    unsigned r;
    asm("v_cvt_pk_bf16_f32 %0, %1, %2" : "=v"(r) : "v"(a), "v"(b));
    return r;
}

__device__ __forceinline__ s16x4 pk4bf(float a, float b, float c, float d) {
    uint2 t = { cvt2bf(a, b), cvt2bf(c, d) };
    return __builtin_bit_cast(s16x4, t);
}

// [v0,v1,v2,v3] -> [v0,0,v1,0,v2,0,v3,0]: token (4gl+r) at virtual k=8gl+2r of a
// K=32 fragment; zeros at odd k contribute nothing. (Verified R10/R12.)
__device__ __forceinline__ s16x8 expand_z(s16x4 c) {
    uint2 u = __builtin_bit_cast(uint2, c);
    uintx4 r = { u.x & 0xFFFFu, u.x >> 16, u.y & 0xFFFFu, u.y >> 16 };
    return __builtin_bit_cast(s16x8, r);
}

// K0: weights fp32 -> bf16
__global__ void wcvt_kernel(const float* __restrict__ qw, const float* __restrict__ pw,
                            short* __restrict__ wqkv, short* __restrict__ wproj) {
    int idx = blockIdx.x * blockDim.x + threadIdx.x;
    int stride = gridDim.x * blockDim.x;
    for (int i = idx; i < 65536; i += stride) {
        const float* src = (i < 49152) ? (qw + i * 4) : (pw + (i - 49152) * 4);
        unsigned* dst = (unsigned*)((i < 49152) ? (wqkv + i * 4) : (wproj + (i - 49152) * 4));
        const f32x4 v = *(const f32x4*)src;
        uint2 o = { cvt2bf(v.x, v.y), cvt2bf(v.z, v.w) };
        *(uint2*)dst = o;
    }
}

// K1: bias+mask table, log2 domain. bm[cls][head][i][j], cls=(wy==7)*2+(wx==7)
__global__ void bmgen_kernel(const float* __restrict__ rpb, float* __restrict__ bm) {
    int idx = blockIdx.x * blockDim.x + threadIdx.x;
    if (idx >= 131072) return;
    int j = idx & 63;
    int i = (idx >> 6) & 63;
    int h = (idx >> 12) & 7;
    int c = idx >> 15;
    int cy = c >> 1, cx = c & 1;
    float v;
    if (j >= 49) {
        v = -1e9f;
    } else {
        int ic = i > 48 ? 48 : i;
        int yi = ic / 7, xi = ic % 7;
        int yj = j / 7, xj = j % 7;
        float bias = rpb[((yi - yj + 6) * 13 + (xi - xj + 6)) * 8 + h];
        int ri = (cy ? (yi < 4 ? 1 : 2) : 0) * 3 + (cx ? (xi < 4 ? 1 : 2) : 0);
        int rj = (cy ? (yj < 4 ? 1 : 2) : 0) * 3 + (cx ? (xj < 4 ? 1 : 2) : 0);
        float mask = (ri != rj) ? -100.0f : 0.0f;
        v = (bias + mask) * 1.4426950408889634f;
    }
    bm[idx] = v;
}

// K2: attention. Block = (window, 4-head group). 8 waves = (hl in 0..3, jh in 0..1).
// Writes la[win*49 + t][256] bf16 (this block's 128 channels).
__global__ __launch_bounds__(512, 4)
void attn_kernel(const float* __restrict__ x,
                 const float* __restrict__ qkv_bias,
                 const short* __restrict__ wqkv,
                 const float* __restrict__ bm,
                 unsigned short* __restrict__ la) {
    __shared__ __align__(16) short buf[64 * LBS];   // x -> Q|K -> lout(f32)
    __shared__ __align__(16) short lvt[128 * VTS];  // V^T, 4 heads (local cols 0..127)
    __shared__ float lml[4 * 64];                   // [hl*64 + i] jh0 partial sums

    const int tid  = threadIdx.x;
    const int w    = tid >> 6;        // wave 0..7
    const int lane = tid & 63;
    const int il   = lane & 15;
    const int gl   = lane >> 4;
    const int hl   = w >> 1;          // head-local 0..3
    const int jh   = w & 1;           // key-half

    const int hg  = blockIdx.x & 1;
    const int win = blockIdx.x >> 1;
    const int wid = win & 63;
    const int b   = win >> 6;
    const int wy  = wid >> 3, wx = wid & 7;

    // ---------------- stage window x (bf16, cols 0..255) --------------------
    // one token row per thread: divmod/roll computed ONCE, 8 fixed-stride loads
    {
        const int t0 = tid >> 3;           // row 0..63
        const int cb = (tid & 7) << 2;     // f32 col base
        const float* xrow = x;             // dummy init
        if (t0 < 49) {
            int ty = t0 / 7, tx = t0 % 7;
            int R = wy * 7 + ty + 3; if (R >= 56) R -= 56;
            int C = wx * 7 + tx + 3; if (C >= 56) C -= 56;
            xrow = x + (((b * 56 + R) * 56 + C) << 8);
        }
        #pragma unroll
        for (int j = 0; j < 8; j++) {
            int c4 = cb + 32 * j;
            uint2 o = { 0u, 0u };
            if (t0 < 49) {
                const f32x4 v = *(const f32x4*)(xrow + c4);
                o.x = cvt2bf(v.x, v.y); o.y = cvt2bf(v.z, v.w);
            }
            *(uint2*)&buf[t0 * LBS + c4] = o;
        }
    }
    __syncthreads();   // (1)

    const int cls = ((wy == 7) ? 2 : 0) + ((wx == 7) ? 1 : 0);
    const float* bmp = bm + ((cls * 8 + hg * 4 + hl) * 64) * 64;
    f32x4 s[2][4];

    // ---------------- QKV GEMM: wave w -> 16 cols each of Q,K,V -------------
    {
        f32x4 acc[4][3];
        #pragma unroll
        for (int mi = 0; mi < 4; mi++)
            #pragma unroll
            for (int t = 0; t < 3; t++) acc[mi][t] = (f32x4){0.f, 0.f, 0.f, 0.f};
        for (int k0 = 0; k0 < 256; k0 += 32) {
            s16x8 a[4];
            #pragma unroll
            for (int mi = 0; mi < 4; mi++)
                a[mi] = *(const s16x8*)&buf[(mi * 16 + il) * LBS + k0 + 8 * gl];
            #pragma unroll
            for (int t = 0; t < 3; t++) {
                s16x8 bfr = *(const s16x8*)(wqkv + (t * 256 + hg * 128 + 16 * w + il) * 256 + k0 + 8 * gl);
                #pragma unroll
                for (int mi = 0; mi < 4; mi++)
                    acc[mi][t] = __builtin_amdgcn_mfma_f32_16x16x32_bf16(a[mi], bfr, acc[mi][t], 0, 0, 0);
            }
        }
        // V -> lvt (transposed; row = local v-col, col = token), disjoint region
        {
            float bv = qkv_bias[512 + hg * 128 + 16 * w + il];
            #pragma unroll
            for (int mi = 0; mi < 4; mi++)
                *(s16x4*)&lvt[(16 * w + il) * VTS + mi * 16 + gl * 4] =
                    pk4bf(acc[mi][2][0] + bv, acc[mi][2][1] + bv,
                          acc[mi][2][2] + bv, acc[mi][2][3] + bv);
        }
        __syncthreads();   // (2) x reads done; buf -> Q|K
        {
            const float QSCL = 0.17677669529663687f * 1.4426950408889634f;
            float bq_ = qkv_bias[hg * 128 + 16 * w + il];
            float bk_ = qkv_bias[256 + hg * 128 + 16 * w + il];
            #pragma unroll
            for (int mi = 0; mi < 4; mi++)
                #pragma unroll
                for (int r = 0; r < 4; r++) {
                    int row = mi * 16 + gl * 4 + r;
                    unsigned u = cvt2bf((acc[mi][0][r] + bq_) * QSCL, acc[mi][1][r] + bk_);
                    buf[row * LBS + 16 * w + il] = (short)u;                 // Q local col
                    buf[row * LBS + 128 + 16 * w + il] = (short)(u >> 16);   // K local col
                }
        }
    }
    // bias+mask C-init loads issued BEFORE the barrier: latency hides in drain
    #pragma unroll
    for (int mi = 0; mi < 2; mi++)
        #pragma unroll
        for (int ni = 0; ni < 4; ni++)
            s[mi][ni] = *(const f32x4*)&bmp[(ni * 16 + il) * 64 + jh * 32 + mi * 16 + gl * 4];
    __syncthreads();   // (3) Q,K,VT ready

    // ---------------- attention: wave (hl, jh), keys [32jh, 32jh+32) --------
    {
        s16x8 bq[4];
        #pragma unroll
        for (int ni = 0; ni < 4; ni++)
            bq[ni] = *(const s16x8*)&buf[(ni * 16 + il) * LBS + hl * 32 + 8 * gl];
        #pragma unroll
        for (int mi = 0; mi < 2; mi++) {
            s16x8 ak = *(const s16x8*)&buf[(jh * 32 + mi * 16 + il) * LBS + 128 + hl * 32 + 8 * gl];
            #pragma unroll
            for (int ni = 0; ni < 4; ni++)
                s[mi][ni] = __builtin_amdgcn_mfma_f32_16x16x32_bf16(ak, bq[ni], s[mi][ni], 0, 0, 0);
        }
    }
    // p = 2^s (log2 domain, no max); partial row sums; pack compact
    float l[4] = { 0.f, 0.f, 0.f, 0.f };
    s16x4 pkd[2][4];
    #pragma unroll
    for (int mi = 0; mi < 2; mi++)
        #pragma unroll
        for (int ni = 0; ni < 4; ni++) {
            float p0 = exp2f(s[mi][ni][0]);
            float p1 = exp2f(s[mi][ni][1]);
            float p2 = exp2f(s[mi][ni][2]);
            float p3 = exp2f(s[mi][ni][3]);
            l[ni] += (p0 + p1) + (p2 + p3);
            pkd[mi][ni] = pk4bf(p0, p1, p2, p3);
        }
    #pragma unroll
    for (int ni = 0; ni < 4; ni++) {
        l[ni] += __shfl_xor(l[ni], 16);
        l[ni] += __shfl_xor(l[ni], 32);
    }
    if (jh == 0 && gl == 0) {
        #pragma unroll
        for (int ni = 0; ni < 4; ni++) lml[hl * 64 + ni * 16 + il] = l[ni];
    }
    __syncthreads();   // (4) lml visible; Q|K frag reads done -> buf free for lout

    // PV: o^T[d][i] += V^T[d][j] P[j][i], zero-shuffle even-k fragments
    f32x4 o[2][4];
    #pragma unroll
    for (int md = 0; md < 2; md++)
        #pragma unroll
        for (int ni = 0; ni < 4; ni++) o[md][ni] = (f32x4){0.f, 0.f, 0.f, 0.f};
    #pragma unroll
    for (int mi = 0; mi < 2; mi++) {
        s16x8 av[2];
        #pragma unroll
        for (int md = 0; md < 2; md++)
            av[md] = expand_z(*(const s16x4*)&lvt[(hl * 32 + md * 16 + il) * VTS + jh * 32 + mi * 16 + 4 * gl]);
        #pragma unroll
        for (int ni = 0; ni < 4; ni++) {
            s16x8 bp = expand_z(pkd[mi][ni]);
            #pragma unroll
            for (int md = 0; md < 2; md++)
                o[md][ni] = __builtin_amdgcn_mfma_f32_16x16x32_bf16(av[md], bp, o[md][ni], 0, 0, 0);
        }
    }
    float* lout = (float*)buf;   // [64][LOS]
    if (jh == 0) {
        #pragma unroll
        for (int md = 0; md < 2; md++)
            #pragma unroll
            for (int ni = 0; ni < 4; ni++)
                *(f32x4*)&lout[(ni * 16 + il) * LOS + hl * 32 + md * 16 + gl * 4] = o[md][ni];
    }
    __syncthreads();   // (5)
    if (jh == 1) {
        float sc[4];
        #pragma unroll
        for (int ni = 0; ni < 4; ni++)
            sc[ni] = __builtin_amdgcn_rcpf(l[ni] + lml[hl * 64 + ni * 16 + il]);
        #pragma unroll
        for (int ni = 0; ni < 4; ni++) {
            int i = ni * 16 + il;
            if (i < 49) {
                #pragma unroll
                for (int md = 0; md < 2; md++) {
                    f32x4 t = *(const f32x4*)&lout[i * LOS + hl * 32 + md * 16 + gl * 4];
                    uint2 pk = { cvt2bf((t.x + o[md][ni][0]) * sc[ni], (t.y + o[md][ni][1]) * sc[ni]),
                                 cvt2bf((t.z + o[md][ni][2]) * sc[ni], (t.w + o[md][ni][3]) * sc[ni]) };
                    *(uint2*)&la[(win * 49 + i) * 256 + hg * 128 + hl * 32 + md * 16 + gl * 4] = pk;
                }
            }
        }
    }
}

// K3: proj GEMM + reverse-roll store. Block = window, 8 waves.
__global__ __launch_bounds__(512, 4)
void proj_kernel(const unsigned short* __restrict__ la,
                 const float* __restrict__ proj_bias,
                 const short* __restrict__ wproj,
                 float* __restrict__ out) {
    __shared__ __align__(16) short buf[64 * LBS];   // la -> fout(bf16)

    const int tid  = threadIdx.x;
    const int w    = tid >> 6;
    const int lane = tid & 63;
    const int il   = lane & 15;
    const int gl   = lane >> 4;

    const int win = blockIdx.x;
    const int wid = win & 63;
    const int b   = win >> 6;
    const int wy  = wid >> 3, wx = wid & 7;

    // stage la (bf16 rows, coalesced, 16B chunks); zero rows 49..63
    for (int i = tid; i < 2048; i += 512) {   // 64 rows x 32 chunks of 8 shorts
        int t = i >> 5, c8 = (i & 31) << 3;
        uintx4 v = (t < 49) ? *(const uintx4*)&la[(win * 49 + t) * 256 + c8]
                            : (uintx4){0u, 0u, 0u, 0u};
        *(uintx4*)&buf[t * LBS + c8] = v;
    }
    __syncthreads();   // (1)

    f32x4 acc[4][2];
    #pragma unroll
    for (int mi = 0; mi < 4; mi++)
        #pragma unroll
        for (int ni = 0; ni < 2; ni++) acc[mi][ni] = (f32x4){0.f, 0.f, 0.f, 0.f};
    for (int k0 = 0; k0 < 256; k0 += 32) {
        s16x8 a[4];
        #pragma unroll
        for (int mi = 0; mi < 4; mi++)
            a[mi] = *(const s16x8*)&buf[(mi * 16 + il) * LBS + k0 + 8 * gl];
        #pragma unroll
        for (int ni = 0; ni < 2; ni++) {
            s16x8 bw = *(const s16x8*)(wproj + (32 * w + 16 * ni + il) * 256 + k0 + 8 * gl);
            #pragma unroll
            for (int mi = 0; mi < 4; mi++)
                acc[mi][ni] = __builtin_amdgcn_mfma_f32_16x16x32_bf16(a[mi], bw, acc[mi][ni], 0, 0, 0);
        }
    }
    __syncthreads();   // (2) la reads done; buf -> fout (bf16)
    #pragma unroll
    for (int ni = 0; ni < 2; ni++) {
        int oc = 32 * w + 16 * ni + il;
        float pb = proj_bias[oc];
        #pragma unroll
        for (int mi = 0; mi < 4; mi++)
            #pragma unroll
            for (int r = 0; r < 4; r++) {
                int t = mi * 16 + gl * 4 + r;
                if (t < 49) {
                    unsigned u = cvt2bf(acc[mi][ni][r] + pb, 0.f);
                    buf[t * LBS + oc] = (short)u;
                }
            }
    }
    __syncthreads();   // (3)
    // coalesced store with reverse roll: full 1KB token rows
    for (int i = tid; i < 1568; i += 512) {   // 49 rows x 32 chunks of 8 floats
        int t = i >> 5, c8 = (i & 31) << 3;
        uintx4 u = *(const uintx4*)&buf[t * LBS + c8];
        f32x4 v0, v1;
        v0.x = __builtin_bit_cast(float, u.x << 16);
        v0.y = __builtin_bit_cast(float, u.x & 0xFFFF0000u);
        v0.z = __builtin_bit_cast(float, u.y << 16);
        v0.w = __builtin_bit_cast(float, u.y & 0xFFFF0000u);
        v1.x = __builtin_bit_cast(float, u.z << 16);
        v1.y = __builtin_bit_cast(float, u.z & 0xFFFF0000u);
        v1.z = __builtin_bit_cast(float, u.w << 16);
        v1.w = __builtin_bit_cast(float, u.w & 0xFFFF0000u);
        int ty = t / 7, tx = t % 7;
        int R = wy * 7 + ty + 3; if (R >= 56) R -= 56;
        int C = wx * 7 + tx + 3; if (C >= 56) C -= 56;
        float* op = out + (((b * 56 + R) * 56 + C) << 8) + c8;
        *(f32x4*)op = v0;
        *(f32x4*)(op + 4) = v1;
    }
}

extern "C" void kernel_launch(void* const* d_in, const int* in_sizes, int n_in,
                              void* d_out, int out_size, void* d_ws, size_t ws_size,
                              hipStream_t stream) {
    const float* x   = (const float*)d_in[0];
    const float* qw  = (const float*)d_in[1];
    const float* qb  = (const float*)d_in[2];
    const float* pw  = (const float*)d_in[3];
    const float* pb  = (const float*)d_in[4];
    const float* rpb = (const float*)d_in[5];

    short* wqkv  = (short*)d_ws;                            // 768*256 bf16
    short* wproj = wqkv + 768 * 256;                        // 256*256 bf16
    float* bmt   = (float*)((char*)d_ws + 524288);          // 4*8*64*64 f32
    unsigned short* lat = (unsigned short*)((char*)d_ws + 2097152);  // 2048*49*256 bf16 = 51.4 MB

    wcvt_kernel<<<128, 256, 0, stream>>>(qw, pw, wqkv, wproj);
    bmgen_kernel<<<512, 256, 0, stream>>>(rpb, bmt);
    attn_kernel<<<4096, 512, 0, stream>>>(x, qb, wqkv, bmt, lat);
    proj_kernel<<<2048, 512, 0, stream>>>(lat, pb, wproj, (float*)d_out);
}